// Round 16
// baseline (117.400 us; speedup 1.0000x reference)
//
#include <hip/hip_runtime.h>
#include <stdint.h>

#define T_STEPS 32
#define DECAY   0.951229424500714f    // exp(-1/20)
#define DECAY16 0.449328964117222f    // exp(-16/20)

typedef __attribute__((ext_vector_type(4))) float f32x4;
typedef __attribute__((ext_vector_type(8))) short bf16x8;

typedef const void __attribute__((address_space(1)))* gptr_t;
typedef void __attribute__((address_space(3)))* sptr_t;

__device__ __forceinline__ unsigned short f2bf(float f) {
    unsigned u = __builtin_bit_cast(unsigned, f);
    return (unsigned short)((u + 0x7FFFu + ((u >> 16) & 1u)) >> 16);
}

// blocks [0, mBlocks): temporal leaky reduce x[M][T][D] -> mem[M][D].
//   NEW: one row per WAVE (4 rows/block) — each wave sweeps its row's
//   128 KiB SEQUENTIALLY (4x 1-KiB loads per 4-KiB t-slice, in address
//   order) for HBM page/channel locality. 8 indep FMA chains per thread.
//   nt loads on the x stream are PROTECTED (R11: removing cost ~10 µs).
// blocks [mBlocks, ...): convert W fp32 -> bf16.
__global__ __launch_bounds__(256) void prep_kernel(
    const float* __restrict__ x, const float* __restrict__ W,
    unsigned short* __restrict__ mem, unsigned short* __restrict__ Wb,
    int mBlocks, int M, int D)
{
    int tid = threadIdx.x;
    if ((int)blockIdx.x < mBlocks) {
        int lane = tid & 63;
        int w    = tid >> 6;
        int row  = blockIdx.x * 4 + w;                 // one row per wave
        const f32x4* xr = (const f32x4*)(x + (size_t)row * T_STEPS * D) + lane;
        // per t-slice (D=1024 floats = 256 f32x4), wave covers 4 chunks of 64
        f32x4 h[4] = {{0.f,0.f,0.f,0.f},{0.f,0.f,0.f,0.f},
                      {0.f,0.f,0.f,0.f},{0.f,0.f,0.f,0.f}};
        f32x4 l[4] = {{0.f,0.f,0.f,0.f},{0.f,0.f,0.f,0.f},
                      {0.f,0.f,0.f,0.f},{0.f,0.f,0.f,0.f}};
        #pragma unroll
        for (int t = 0; t < 16; ++t) {
            #pragma unroll
            for (int q = 0; q < 4; ++q) {
                f32x4 a = __builtin_nontemporal_load(&xr[(size_t)t * 256 + q * 64]);
                h[q] = h[q] * DECAY + a;
            }
        }
        #pragma unroll
        for (int t = 16; t < 32; ++t) {
            #pragma unroll
            for (int q = 0; q < 4; ++q) {
                f32x4 a = __builtin_nontemporal_load(&xr[(size_t)t * 256 + q * 64]);
                l[q] = l[q] * DECAY + a;
            }
        }
        unsigned short* mr = mem + (size_t)row * D + lane * 4;
        #pragma unroll
        for (int q = 0; q < 4; ++q) {
            f32x4 r = h[q] * DECAY16 + l[q];
            ushort4 o;
            o.x = f2bf(r.x); o.y = f2bf(r.y); o.z = f2bf(r.z); o.w = f2bf(r.w);
            *(ushort4*)(mr + q * 256) = o;
        }
    } else {
        int idx = (blockIdx.x - mBlocks) * 256 + tid;
        f32x4 v = ((const f32x4*)W)[idx];
        ushort4 o;
        o.x = f2bf(v.x); o.y = f2bf(v.y); o.z = f2bf(v.z); o.w = f2bf(v.w);
        *(ushort4*)(Wb + (size_t)idx * 4) = o;
    }
}

// C[M][N] = A[M][K] @ B[N][K]^T + bias, bf16 inputs, fp32 out
// (byte-identical to R12 champion: 64x128 tile, pair-step K-loop, 6 LDS
//  buffers, one barrier + one counted vmcnt per TWO K-steps, chunk swizzle)
#define BM 64
#define BN 128
#define BK 32
#define NBUF 6

__global__ __launch_bounds__(256) void gemm_kernel(
    const unsigned short* __restrict__ A,    // mem bf16 [M][K]
    const unsigned short* __restrict__ Bw,   // W bf16 [N][K]
    const float* __restrict__ bias,          // [N]
    float* __restrict__ C,                   // [M][N]
    int M, int N, int K)
{
    __shared__ unsigned short As[NBUF][BM][BK];   // 6 x 4 KiB
    __shared__ unsigned short Bs[NBUF][BN][BK];   // 6 x 8 KiB  (72 KiB total)

    // XCD-aware swizzle (grid=512, 512%8==0 -> bijective)
    int nwg = gridDim.x;
    int cpx = nwg >> 3;
    int bid = (int)blockIdx.x;
    int wg  = (bid & 7) * cpx + (bid >> 3);

    int nbn = N / BN;
    int bm = wg / nbn;
    int bn = wg % nbn;

    int tid  = threadIdx.x;
    int lane = tid & 63;
    int wid  = tid >> 6;         // 0..3
    int wr   = wid >> 1;         // wave row block (32 rows)
    int wc   = wid & 1;          // wave col block (64 cols)

    // staging: LDS dest byte = 16*tid (linear). Global source col swizzled:
    // thread covers (srow, chunk=tid&3); source chunk = chunk ^ ((srow>>1)&3).
    int srow    = tid >> 2;                              // 0..63
    int swchunk = (tid & 3) ^ ((srow >> 1) & 3);
    int swcol   = swchunk << 3;                          // bf16 units

    const unsigned short* Ag  = A  + (size_t)(bm * BM + srow) * K + swcol;
    const unsigned short* Bg0 = Bw + (size_t)(bn * BN + srow) * K + swcol;
    const unsigned short* Bg1 = Bw + (size_t)(bn * BN + 64 + srow) * K + swcol;
    // (64+srow)>>1 & 3 == (srow>>1)&3 since 32%4==0 — swizzle class consistent.

    f32x4 acc[2][4] = {};

    int fr = lane & 15;          // row within 16x16 fragment
    // swizzled lane-constant 16B offset: chunk c=lane>>4, XOR (fr>>1)&3
    int swoff = (((lane >> 4) ^ ((fr >> 1) & 3)) << 4);  // bytes

    auto stage = [&](int b, int kt) {
        int k0 = kt * BK;
        __builtin_amdgcn_global_load_lds((gptr_t)(Ag  + k0), (sptr_t)(&As[b][srow][(tid & 3) << 3]),      16, 0, 0);
        __builtin_amdgcn_global_load_lds((gptr_t)(Bg0 + k0), (sptr_t)(&Bs[b][srow][(tid & 3) << 3]),      16, 0, 0);
        __builtin_amdgcn_global_load_lds((gptr_t)(Bg1 + k0), (sptr_t)(&Bs[b][64 + srow][(tid & 3) << 3]), 16, 0, 0);
    };

    auto compute = [&](int b) {
        const char* Ab = (const char*)&As[b][0][0];
        const char* Bb = (const char*)&Bs[b][0][0];
        bf16x8 a0 = *(const bf16x8*)(Ab + (wr * 32 +      fr) * 64 + swoff);
        bf16x8 a1 = *(const bf16x8*)(Ab + (wr * 32 + 16 + fr) * 64 + swoff);
        bf16x8 b0 = *(const bf16x8*)(Bb + (wc * 64 +      fr) * 64 + swoff);
        bf16x8 b1 = *(const bf16x8*)(Bb + (wc * 64 + 16 + fr) * 64 + swoff);
        bf16x8 b2 = *(const bf16x8*)(Bb + (wc * 64 + 32 + fr) * 64 + swoff);
        bf16x8 b3 = *(const bf16x8*)(Bb + (wc * 64 + 48 + fr) * 64 + swoff);

        acc[0][0] = __builtin_amdgcn_mfma_f32_16x16x32_bf16(a0, b0, acc[0][0], 0, 0, 0);
        acc[0][1] = __builtin_amdgcn_mfma_f32_16x16x32_bf16(a0, b1, acc[0][1], 0, 0, 0);
        acc[0][2] = __builtin_amdgcn_mfma_f32_16x16x32_bf16(a0, b2, acc[0][2], 0, 0, 0);
        acc[0][3] = __builtin_amdgcn_mfma_f32_16x16x32_bf16(a0, b3, acc[0][3], 0, 0, 0);
        acc[1][0] = __builtin_amdgcn_mfma_f32_16x16x32_bf16(a1, b0, acc[1][0], 0, 0, 0);
        acc[1][1] = __builtin_amdgcn_mfma_f32_16x16x32_bf16(a1, b1, acc[1][1], 0, 0, 0);
        acc[1][2] = __builtin_amdgcn_mfma_f32_16x16x32_bf16(a1, b2, acc[1][2], 0, 0, 0);
        acc[1][3] = __builtin_amdgcn_mfma_f32_16x16x32_bf16(a1, b3, acc[1][3], 0, 0, 0);
    };

    int nk = K / BK;             // 32 (even)

    stage(0, 0);
    stage(1, 1);
    stage(2, 2);
    stage(3, 3);                 // 12 loads outstanding

    for (int kt = 0; kt < nk; kt += 2) {
        // stages kt,kt+1 landed; kt+2,kt+3 still in flight (never drain mid-loop)
        if (kt + 2 < nk) {
            asm volatile("s_waitcnt vmcnt(6)" ::: "memory");
        } else {
            asm volatile("s_waitcnt vmcnt(0)" ::: "memory");
        }
        // one barrier per pair: all waves past compute(kt-2),(kt-1) — so
        // staging bufs (kt+4)%6,(kt+5)%6 (last read at kt-2,kt-1) is safe.
        __builtin_amdgcn_s_barrier();

        if (kt + 4 < nk) stage((kt + 4) % NBUF, kt + 4);
        if (kt + 5 < nk) stage((kt + 5) % NBUF, kt + 5);

        compute(kt % NBUF);
        compute((kt + 1) % NBUF);
    }

    // C/D layout: col = lane&15, row = (lane>>4)*4 + reg
    int fc  = lane & 15;
    int fq  = (lane >> 4) << 2;
    int row0 = bm * BM + wr * 32;
    int col0 = bn * BN + wc * 64;
    #pragma unroll
    for (int mi = 0; mi < 2; ++mi) {
        #pragma unroll
        for (int ni = 0; ni < 4; ++ni) {
            int col = col0 + ni * 16 + fc;
            float bv = bias[col];
            #pragma unroll
            for (int r = 0; r < 4; ++r) {
                int row = row0 + mi * 16 + fq + r;
                __builtin_nontemporal_store(acc[mi][ni][r] + bv, &C[(size_t)row * N + col]);
            }
        }
    }
}

extern "C" void kernel_launch(void* const* d_in, const int* in_sizes, int n_in,
                              void* d_out, int out_size, void* d_ws, size_t ws_size,
                              hipStream_t stream) {
    const float* x    = (const float*)d_in[0];
    const float* W    = (const float*)d_in[1];
    const float* bias = (const float*)d_in[2];
    float* out = (float*)d_out;

    int Dout = in_sizes[2];                   // 1024
    int Din  = in_sizes[1] / Dout;            // 1024
    int M    = in_sizes[0] / (T_STEPS * Din); // 4096 (= B*S)

    unsigned short* mem = (unsigned short*)d_ws;                      // M*Din bf16
    unsigned short* Wb  = (unsigned short*)d_ws + (size_t)M * Din;    // Dout*Din bf16

    int mBlocks = M / 4;                      // 1024 (one row per wave)
    int wBlocks = (Dout * Din) / (4 * 256);   // 1024
    prep_kernel<<<mBlocks + wBlocks, 256, 0, stream>>>(x, W, mem, Wb, mBlocks, M, Din);

    int grid = (M / BM) * (Dout / BN);        // 512
    gemm_kernel<<<grid, 256, 0, stream>>>(mem, Wb, bias, out, M, Dout, Din);
}

// Round 17
// 113.543 us; speedup vs baseline: 1.0340x; 1.0340x over previous
//
#include <hip/hip_runtime.h>
#include <stdint.h>

#define T_STEPS 32
#define DECAY   0.951229424500714f    // exp(-1/20)
#define DECAY16 0.449328964117222f    // exp(-16/20)

typedef __attribute__((ext_vector_type(4))) float f32x4;
typedef __attribute__((ext_vector_type(8))) short bf16x8;

typedef const void __attribute__((address_space(1)))* gptr_t;
typedef void __attribute__((address_space(3)))* sptr_t;

__device__ __forceinline__ unsigned short f2bf(float f) {
    unsigned u = __builtin_bit_cast(unsigned, f);
    return (unsigned short)((u + 0x7FFFu + ((u >> 16) & 1u)) >> 16);
}

// blocks [0, mBlocks): temporal leaky reduce x[M][T][D] -> mem[M][D] (bf16)
// blocks [mBlocks, ...): convert W fp32 -> bf16
// (byte-identical to R12 champion prep — all pattern variants regressed;
//  nt loads PROTECTED)
__global__ __launch_bounds__(256) void prep_kernel(
    const float* __restrict__ x, const float* __restrict__ W,
    unsigned short* __restrict__ mem, unsigned short* __restrict__ Wb,
    int mBlocks, int M, int D)
{
    if ((int)blockIdx.x < mBlocks) {
        int idx = blockIdx.x * 256 + threadIdx.x;   // one per 4 floats of mem
        int perRow = D >> 2;                        // float4 per row
        int m = idx / perRow;
        int d4 = idx - m * perRow;
        if (m >= M) return;
        const f32x4* xr = (const f32x4*)(x + (size_t)m * T_STEPS * D) + d4;
        f32x4 accH = {0.f, 0.f, 0.f, 0.f};
        f32x4 accL = {0.f, 0.f, 0.f, 0.f};
        #pragma unroll
        for (int t = 0; t < 16; ++t) {
            f32x4 vh = __builtin_nontemporal_load(&xr[(size_t)t * perRow]);
            f32x4 vl = __builtin_nontemporal_load(&xr[(size_t)(t + 16) * perRow]);
            accH = accH * DECAY + vh;
            accL = accL * DECAY + vl;
        }
        f32x4 acc = accH * DECAY16 + accL;
        ushort4 o;
        o.x = f2bf(acc.x); o.y = f2bf(acc.y); o.z = f2bf(acc.z); o.w = f2bf(acc.w);
        *(ushort4*)(mem + (size_t)idx * 4) = o;
    } else {
        int idx = (blockIdx.x - mBlocks) * 256 + threadIdx.x;
        f32x4 v = ((const f32x4*)W)[idx];
        ushort4 o;
        o.x = f2bf(v.x); o.y = f2bf(v.y); o.z = f2bf(v.z); o.w = f2bf(v.w);
        *(ushort4*)(Wb + (size_t)idx * 4) = o;
    }
}

// C[M][N] = A[M][K] @ B[N][K]^T + bias, bf16 inputs, fp32 out
// CHANGE vs R12: 128x128 tile, 4 waves of 64x64 (2x FLOP per LDS byte:
// 48 KiB/K-step/CU vs 72) — R4's shape FIXED with chunk swizzle (R4's
// 8-way conflict was its real cost) + pair-step + 6 buffers (96 KiB LDS,
// 1 block/CU) + counted vmcnt(8).
#define BM 128
#define BN 128
#define BK 32
#define NBUF 6

__global__ __launch_bounds__(256) void gemm_kernel(
    const unsigned short* __restrict__ A,    // mem bf16 [M][K]
    const unsigned short* __restrict__ Bw,   // W bf16 [N][K]
    const float* __restrict__ bias,          // [N]
    float* __restrict__ C,                   // [M][N]
    int M, int N, int K)
{
    __shared__ unsigned short As[NBUF][BM][BK];   // 6 x 8 KiB
    __shared__ unsigned short Bs[NBUF][BN][BK];   // 6 x 8 KiB  (96 KiB total)

    // XCD-aware swizzle (grid=256, 256%8==0 -> bijective), bm-major:
    // each XCD owns 4 bm-bands x 8 bn -> A 1 MiB + W 2 MiB in its L2.
    int nwg = gridDim.x;
    int cpx = nwg >> 3;
    int bid = (int)blockIdx.x;
    int wg  = (bid & 7) * cpx + (bid >> 3);

    int nbn = N / BN;            // 8
    int bm = wg / nbn;
    int bn = wg % nbn;

    int tid  = threadIdx.x;
    int lane = tid & 63;
    int wid  = tid >> 6;         // 0..3
    int wr   = wid >> 1;         // wave row block (64 rows)
    int wc   = wid & 1;          // wave col block (64 cols)

    // staging: LDS dest byte = 16*tid within each 64-row half (linear, rule 21).
    // Global source col swizzled: chunk' = chunk ^ ((srow>>1)&3).
    int srow    = tid >> 2;                              // 0..63
    int swchunk = (tid & 3) ^ ((srow >> 1) & 3);
    int swcol   = swchunk << 3;                          // bf16 units

    const unsigned short* Ag0 = A  + (size_t)(bm * BM + srow) * K + swcol;
    const unsigned short* Ag1 = A  + (size_t)(bm * BM + 64 + srow) * K + swcol;
    const unsigned short* Bg0 = Bw + (size_t)(bn * BN + srow) * K + swcol;
    const unsigned short* Bg1 = Bw + (size_t)(bn * BN + 64 + srow) * K + swcol;
    // (64+srow)>>1&3 == (srow>>1)&3 (64%8==0) — swizzle class consistent.

    f32x4 acc[4][4] = {};

    int fr = lane & 15;          // row within 16x16 fragment
    // lane-constant swizzled 16B offset: rows are 16*i+fr, (16i>>1)&3==0
    int swoff = (((lane >> 4) ^ ((fr >> 1) & 3)) << 4);  // bytes

    auto stage = [&](int b, int kt) {
        int k0 = kt * BK;
        __builtin_amdgcn_global_load_lds((gptr_t)(Ag0 + k0), (sptr_t)(&As[b][srow][(tid & 3) << 3]),      16, 0, 0);
        __builtin_amdgcn_global_load_lds((gptr_t)(Ag1 + k0), (sptr_t)(&As[b][64 + srow][(tid & 3) << 3]), 16, 0, 0);
        __builtin_amdgcn_global_load_lds((gptr_t)(Bg0 + k0), (sptr_t)(&Bs[b][srow][(tid & 3) << 3]),      16, 0, 0);
        __builtin_amdgcn_global_load_lds((gptr_t)(Bg1 + k0), (sptr_t)(&Bs[b][64 + srow][(tid & 3) << 3]), 16, 0, 0);
    };

    auto compute = [&](int b) {
        const char* Ab = (const char*)&As[b][0][0];
        const char* Bb = (const char*)&Bs[b][0][0];
        bf16x8 a[4], bb[4];
        #pragma unroll
        for (int i = 0; i < 4; ++i) {
            a[i]  = *(const bf16x8*)(Ab + (wr * 64 + i * 16 + fr) * 64 + swoff);
            bb[i] = *(const bf16x8*)(Bb + (wc * 64 + i * 16 + fr) * 64 + swoff);
        }
        #pragma unroll
        for (int mi = 0; mi < 4; ++mi)
            #pragma unroll
            for (int ni = 0; ni < 4; ++ni)
                acc[mi][ni] = __builtin_amdgcn_mfma_f32_16x16x32_bf16(
                    a[mi], bb[ni], acc[mi][ni], 0, 0, 0);
    };

    int nk = K / BK;             // 32 (even)

    stage(0, 0);
    stage(1, 1);
    stage(2, 2);
    stage(3, 3);                 // 16 loads outstanding

    for (int kt = 0; kt < nk; kt += 2) {
        // stages kt,kt+1 landed; kt+2,kt+3 (8 loads) still in flight
        if (kt + 2 < nk) {
            asm volatile("s_waitcnt vmcnt(8)" ::: "memory");
        } else {
            asm volatile("s_waitcnt vmcnt(0)" ::: "memory");
        }
        // one barrier per pair: all waves past compute(kt-2),(kt-1) — so
        // staging bufs (kt+4)%6,(kt+5)%6 (last read at kt-2,kt-1) is safe.
        __builtin_amdgcn_s_barrier();

        if (kt + 4 < nk) stage((kt + 4) % NBUF, kt + 4);
        if (kt + 5 < nk) stage((kt + 5) % NBUF, kt + 5);

        compute(kt % NBUF);
        compute((kt + 1) % NBUF);
    }

    // C/D layout: col = lane&15, row = (lane>>4)*4 + reg
    int fq  = (lane >> 4) << 2;
    int row0 = bm * BM + wr * 64;
    int col0 = bn * BN + wc * 64;
    #pragma unroll
    for (int mi = 0; mi < 4; ++mi) {
        #pragma unroll
        for (int ni = 0; ni < 4; ++ni) {
            int col = col0 + ni * 16 + fr;
            float bv = bias[col];
            #pragma unroll
            for (int r = 0; r < 4; ++r) {
                int row = row0 + mi * 16 + fq + r;
                __builtin_nontemporal_store(acc[mi][ni][r] + bv, &C[(size_t)row * N + col]);
            }
        }
    }
}

extern "C" void kernel_launch(void* const* d_in, const int* in_sizes, int n_in,
                              void* d_out, int out_size, void* d_ws, size_t ws_size,
                              hipStream_t stream) {
    const float* x    = (const float*)d_in[0];
    const float* W    = (const float*)d_in[1];
    const float* bias = (const float*)d_in[2];
    float* out = (float*)d_out;

    int Dout = in_sizes[2];                   // 1024
    int Din  = in_sizes[1] / Dout;            // 1024
    int M    = in_sizes[0] / (T_STEPS * Din); // 4096 (= B*S)

    unsigned short* mem = (unsigned short*)d_ws;                      // M*Din bf16
    unsigned short* Wb  = (unsigned short*)d_ws + (size_t)M * Din;    // Dout*Din bf16

    int mBlocks = (M * Din) / (4 * 256);      // 4096
    int wBlocks = (Dout * Din) / (4 * 256);   // 1024
    prep_kernel<<<mBlocks + wBlocks, 256, 0, stream>>>(x, W, mem, Wb, mBlocks, M, Din);

    int grid = (M / BM) * (Dout / BN);        // 256
    gemm_kernel<<<grid, 256, 0, stream>>>(mem, Wb, bias, out, M, Dout, Din);
}

// Round 18
// 109.854 us; speedup vs baseline: 1.0687x; 1.0336x over previous
//
#include <hip/hip_runtime.h>
#include <stdint.h>

#define T_STEPS 32
#define DECAY   0.951229424500714f    // exp(-1/20)
#define DECAY16 0.449328964117222f    // exp(-16/20)

typedef __attribute__((ext_vector_type(4))) float f32x4;
typedef __attribute__((ext_vector_type(8))) short bf16x8;

typedef const void __attribute__((address_space(1)))* gptr_t;
typedef void __attribute__((address_space(3)))* sptr_t;

__device__ __forceinline__ unsigned short f2bf(float f) {
    unsigned u = __builtin_bit_cast(unsigned, f);
    return (unsigned short)((u + 0x7FFFu + ((u >> 16) & 1u)) >> 16);
}

// blocks [0, mBlocks): temporal leaky reduce x[M][T][D] -> mem[M][D] (bf16)
// blocks [mBlocks, ...): convert W fp32 -> bf16
// (R12 champion prep — nt loads PROTECTED; all pattern variants regressed)
__global__ __launch_bounds__(256) void prep_kernel(
    const float* __restrict__ x, const float* __restrict__ W,
    unsigned short* __restrict__ mem, unsigned short* __restrict__ Wb,
    int mBlocks, int M, int D)
{
    if ((int)blockIdx.x < mBlocks) {
        int idx = blockIdx.x * 256 + threadIdx.x;   // one per 4 floats of mem
        int perRow = D >> 2;                        // float4 per row
        int m = idx / perRow;
        int d4 = idx - m * perRow;
        if (m >= M) return;
        const f32x4* xr = (const f32x4*)(x + (size_t)m * T_STEPS * D) + d4;
        // two independent 16-long chains for load ILP; result = hi*d^16 + lo
        f32x4 accH = {0.f, 0.f, 0.f, 0.f};
        f32x4 accL = {0.f, 0.f, 0.f, 0.f};
        #pragma unroll
        for (int t = 0; t < 16; ++t) {
            f32x4 vh = __builtin_nontemporal_load(&xr[(size_t)t * perRow]);
            f32x4 vl = __builtin_nontemporal_load(&xr[(size_t)(t + 16) * perRow]);
            accH = accH * DECAY + vh;
            accL = accL * DECAY + vl;
        }
        f32x4 acc = accH * DECAY16 + accL;
        ushort4 o;
        o.x = f2bf(acc.x); o.y = f2bf(acc.y); o.z = f2bf(acc.z); o.w = f2bf(acc.w);
        *(ushort4*)(mem + (size_t)idx * 4) = o;
    } else {
        int idx = (blockIdx.x - mBlocks) * 256 + threadIdx.x;
        f32x4 v = ((const f32x4*)W)[idx];
        ushort4 o;
        o.x = f2bf(v.x); o.y = f2bf(v.y); o.z = f2bf(v.z); o.w = f2bf(v.w);
        *(ushort4*)(Wb + (size_t)idx * 4) = o;
    }
}

// C[M][N] = A[M][K] @ B[N][K]^T + bias, bf16 inputs, fp32 out
// (R12 champion: 64x128 tile, pair-step K-loop, 6 LDS buffers, one barrier +
//  one counted vmcnt per TWO K-steps, chunk swizzle, XCD swizzle, NT C-stores)
#define BM 64
#define BN 128
#define BK 32
#define NBUF 6

__global__ __launch_bounds__(256) void gemm_kernel(
    const unsigned short* __restrict__ A,    // mem bf16 [M][K]
    const unsigned short* __restrict__ Bw,   // W bf16 [N][K]
    const float* __restrict__ bias,          // [N]
    float* __restrict__ C,                   // [M][N]
    int M, int N, int K)
{
    __shared__ unsigned short As[NBUF][BM][BK];   // 6 x 4 KiB
    __shared__ unsigned short Bs[NBUF][BN][BK];   // 6 x 8 KiB  (72 KiB total)

    // XCD-aware swizzle (grid=512, 512%8==0 -> bijective)
    int nwg = gridDim.x;
    int cpx = nwg >> 3;
    int bid = (int)blockIdx.x;
    int wg  = (bid & 7) * cpx + (bid >> 3);

    int nbn = N / BN;
    int bm = wg / nbn;
    int bn = wg % nbn;

    int tid  = threadIdx.x;
    int lane = tid & 63;
    int wid  = tid >> 6;         // 0..3
    int wr   = wid >> 1;         // wave row block (32 rows)
    int wc   = wid & 1;          // wave col block (64 cols)

    // staging: LDS dest byte = 16*tid (linear). Global source col swizzled:
    // thread covers (srow, chunk=tid&3); source chunk = chunk ^ ((srow>>1)&3).
    int srow    = tid >> 2;                              // 0..63
    int swchunk = (tid & 3) ^ ((srow >> 1) & 3);
    int swcol   = swchunk << 3;                          // bf16 units

    const unsigned short* Ag  = A  + (size_t)(bm * BM + srow) * K + swcol;
    const unsigned short* Bg0 = Bw + (size_t)(bn * BN + srow) * K + swcol;
    const unsigned short* Bg1 = Bw + (size_t)(bn * BN + 64 + srow) * K + swcol;
    // (64+srow)>>1 & 3 == (srow>>1)&3 since 32%4==0 — swizzle class consistent.

    f32x4 acc[2][4] = {};

    int fr = lane & 15;          // row within 16x16 fragment
    // swizzled lane-constant 16B offset: chunk c=lane>>4, XOR (fr>>1)&3
    int swoff = (((lane >> 4) ^ ((fr >> 1) & 3)) << 4);  // bytes

    auto stage = [&](int b, int kt) {
        int k0 = kt * BK;
        __builtin_amdgcn_global_load_lds((gptr_t)(Ag  + k0), (sptr_t)(&As[b][srow][(tid & 3) << 3]),      16, 0, 0);
        __builtin_amdgcn_global_load_lds((gptr_t)(Bg0 + k0), (sptr_t)(&Bs[b][srow][(tid & 3) << 3]),      16, 0, 0);
        __builtin_amdgcn_global_load_lds((gptr_t)(Bg1 + k0), (sptr_t)(&Bs[b][64 + srow][(tid & 3) << 3]), 16, 0, 0);
    };

    auto compute = [&](int b) {
        const char* Ab = (const char*)&As[b][0][0];
        const char* Bb = (const char*)&Bs[b][0][0];
        bf16x8 a0 = *(const bf16x8*)(Ab + (wr * 32 +      fr) * 64 + swoff);
        bf16x8 a1 = *(const bf16x8*)(Ab + (wr * 32 + 16 + fr) * 64 + swoff);
        bf16x8 b0 = *(const bf16x8*)(Bb + (wc * 64 +      fr) * 64 + swoff);
        bf16x8 b1 = *(const bf16x8*)(Bb + (wc * 64 + 16 + fr) * 64 + swoff);
        bf16x8 b2 = *(const bf16x8*)(Bb + (wc * 64 + 32 + fr) * 64 + swoff);
        bf16x8 b3 = *(const bf16x8*)(Bb + (wc * 64 + 48 + fr) * 64 + swoff);

        acc[0][0] = __builtin_amdgcn_mfma_f32_16x16x32_bf16(a0, b0, acc[0][0], 0, 0, 0);
        acc[0][1] = __builtin_amdgcn_mfma_f32_16x16x32_bf16(a0, b1, acc[0][1], 0, 0, 0);
        acc[0][2] = __builtin_amdgcn_mfma_f32_16x16x32_bf16(a0, b2, acc[0][2], 0, 0, 0);
        acc[0][3] = __builtin_amdgcn_mfma_f32_16x16x32_bf16(a0, b3, acc[0][3], 0, 0, 0);
        acc[1][0] = __builtin_amdgcn_mfma_f32_16x16x32_bf16(a1, b0, acc[1][0], 0, 0, 0);
        acc[1][1] = __builtin_amdgcn_mfma_f32_16x16x32_bf16(a1, b1, acc[1][1], 0, 0, 0);
        acc[1][2] = __builtin_amdgcn_mfma_f32_16x16x32_bf16(a1, b2, acc[1][2], 0, 0, 0);
        acc[1][3] = __builtin_amdgcn_mfma_f32_16x16x32_bf16(a1, b3, acc[1][3], 0, 0, 0);
    };

    int nk = K / BK;             // 32 (even)

    stage(0, 0);
    stage(1, 1);
    stage(2, 2);
    stage(3, 3);                 // 12 loads outstanding

    for (int kt = 0; kt < nk; kt += 2) {
        // stages kt,kt+1 landed; kt+2,kt+3 still in flight (never drain mid-loop)
        if (kt + 2 < nk) {
            asm volatile("s_waitcnt vmcnt(6)" ::: "memory");
        } else {
            asm volatile("s_waitcnt vmcnt(0)" ::: "memory");
        }
        // one barrier per pair: all waves past compute(kt-2),(kt-1) — so
        // staging bufs (kt+4)%6,(kt+5)%6 (last read at kt-2,kt-1) is safe.
        __builtin_amdgcn_s_barrier();

        if (kt + 4 < nk) stage((kt + 4) % NBUF, kt + 4);
        if (kt + 5 < nk) stage((kt + 5) % NBUF, kt + 5);

        compute(kt % NBUF);
        compute((kt + 1) % NBUF);
    }

    // C/D layout: col = lane&15, row = (lane>>4)*4 + reg
    int fc  = lane & 15;
    int fq  = (lane >> 4) << 2;
    int row0 = bm * BM + wr * 32;
    int col0 = bn * BN + wc * 64;
    #pragma unroll
    for (int mi = 0; mi < 2; ++mi) {
        #pragma unroll
        for (int ni = 0; ni < 4; ++ni) {
            int col = col0 + ni * 16 + fc;
            float bv = bias[col];
            #pragma unroll
            for (int r = 0; r < 4; ++r) {
                int row = row0 + mi * 16 + fq + r;
                __builtin_nontemporal_store(acc[mi][ni][r] + bv, &C[(size_t)row * N + col]);
            }
        }
    }
}

extern "C" void kernel_launch(void* const* d_in, const int* in_sizes, int n_in,
                              void* d_out, int out_size, void* d_ws, size_t ws_size,
                              hipStream_t stream) {
    const float* x    = (const float*)d_in[0];
    const float* W    = (const float*)d_in[1];
    const float* bias = (const float*)d_in[2];
    float* out = (float*)d_out;

    int Dout = in_sizes[2];                   // 1024
    int Din  = in_sizes[1] / Dout;            // 1024
    int M    = in_sizes[0] / (T_STEPS * Din); // 4096 (= B*S)

    unsigned short* mem = (unsigned short*)d_ws;                      // M*Din bf16
    unsigned short* Wb  = (unsigned short*)d_ws + (size_t)M * Din;    // Dout*Din bf16

    int mBlocks = (M * Din) / (4 * 256);      // 4096
    int wBlocks = (Dout * Din) / (4 * 256);   // 1024
    prep_kernel<<<mBlocks + wBlocks, 256, 0, stream>>>(x, W, mem, Wb, mBlocks, M, Din);

    int grid = (M / BM) * (Dout / BN);        // 512
    gemm_kernel<<<grid, 256, 0, stream>>>(mem, Wb, bias, out, M, Dout, Din);
}